// Round 6
// baseline (280.100 us; speedup 1.0000x reference)
//
#include <hip/hip_runtime.h>
#include <stdint.h>

#define NX (8192*512)   // elements of one (B*N, E) matrix
#define NW (512*512)    // elements of one weight matrix

typedef __bf16 bf16x8 __attribute__((ext_vector_type(8)));
typedef float  f32x4  __attribute__((ext_vector_type(4)));

__device__ __forceinline__ unsigned short f2bf(float f){
  unsigned u = __builtin_bit_cast(unsigned, f);
  u += 0x7FFFu + ((u >> 16) & 1u);   // RNE
  return (unsigned short)(u >> 16);
}

__device__ __forceinline__ f32x4 mfma16(bf16x8 a, bf16x8 b, f32x4 c){
  return __builtin_amdgcn_mfma_f32_16x16x32_bf16(a, b, c, 0, 0, 0);
}

__device__ __forceinline__ void gload_lds16(const void* g, void* l){
  __builtin_amdgcn_global_load_lds((const __attribute__((address_space(1))) void*)g,
                                   (__attribute__((address_space(3))) void*)l, 16, 0, 0);
}

// Drain outstanding global_load_lds before a publishing barrier.
__device__ __forceinline__ void drain_vm(){
  asm volatile("s_waitcnt vmcnt(0)" ::: "memory");
}

// ---------------- fp32 -> bf16 conversion of X (q,k,v) and weights ----------------
__global__ void convert_all(const float* __restrict__ q, const float* __restrict__ k,
                            const float* __restrict__ v, const float* __restrict__ wq,
                            const float* __restrict__ wk, const float* __restrict__ wv,
                            const float* __restrict__ wo, unsigned short* __restrict__ dst)
{
  const long total4 = (3L*NX + 4L*NW) / 4;
  for (long i = (long)blockIdx.x*blockDim.x + threadIdx.x; i < total4; i += (long)gridDim.x*blockDim.x){
    long e = i*4;
    const float* src; long off;
    if (e < NX)            { src = q;  off = e; }
    else if (e < 2L*NX)    { src = k;  off = e - NX; }
    else if (e < 3L*NX)    { src = v;  off = e - 2L*NX; }
    else {
      long w = e - 3L*NX; int wi = (int)(w / NW); off = w - (long)wi*NW;
      src = (wi==0) ? wq : (wi==1) ? wk : (wi==2) ? wv : wo;
    }
    float4 f = *(const float4*)(src + off);
    ushort4 o; o.x=f2bf(f.x); o.y=f2bf(f.y); o.z=f2bf(f.z); o.w=f2bf(f.w);
    *(ushort4*)(dst + e) = o;
  }
}

// ---------------- bf16 GEMM: C[m][n] = sum_k A[m][k]*B[n][k] (+bias) ----------------
struct GArg {
  const unsigned short* A;
  const unsigned short* B;
  const float* bias;
  void* C;
  float scale;
  int mode;
};

__global__ __launch_bounds__(256) void gemm_bt(GArg g0, GArg g1, GArg g2)
{
  GArg g = (blockIdx.z==0) ? g0 : (blockIdx.z==1) ? g1 : g2;
  __shared__ __attribute__((aligned(16))) unsigned char lds[65536];
  const int tid  = threadIdx.x;
  const int lane = tid & 63;
  const int wid  = tid >> 6;
  const int wr = wid >> 1, wc = wid & 1;
  const int m0 = blockIdx.y * 128;
  const int n0 = blockIdx.x * 128;

  f32x4 acc[4][4];
  #pragma unroll
  for (int s=0;s<4;s++)
    #pragma unroll
    for (int t=0;t<4;t++) acc[s][t] = (f32x4){0.f,0.f,0.f,0.f};

  auto stage = [&](int kt, int buf){
    int Lb = tid*16;
    #pragma unroll
    for (int i=0;i<4;i++){
      int L = Lb + i*4096;
      int row = L >> 7;
      int innerS = (L & 127) ^ ((row & 7) << 4);   // pre-swizzled source (T2)
      gload_lds16(g.A + (size_t)(m0+row)*512 + kt*64 + (innerS>>1), lds + buf*16384 + L);
    }
    #pragma unroll
    for (int i=0;i<4;i++){
      int L = Lb + i*4096;
      int row = L >> 7;
      int innerS = (L & 127) ^ ((row & 7) << 4);
      gload_lds16(g.B + (size_t)(n0+row)*512 + kt*64 + (innerS>>1), lds + 32768 + buf*16384 + L);
    }
  };

  stage(0, 0);
  drain_vm();
  __syncthreads();

  for (int kt=0; kt<8; kt++){
    int cur = kt & 1;
    if (kt < 7) stage(kt+1, cur^1);
    const unsigned char* LA = lds + cur*16384;
    const unsigned char* LB = lds + 32768 + cur*16384;
    #pragma unroll
    for (int ks=0; ks<2; ks++){
      bf16x8 af[4], bfr[4];
      #pragma unroll
      for (int s=0;s<4;s++){
        int row = wr*64 + s*16 + (lane & 15);
        int inner = (ks*32 + (lane>>4)*8)*2;
        af[s] = *(const bf16x8*)(LA + row*128 + (inner ^ ((row&7)<<4)));
      }
      #pragma unroll
      for (int t=0;t<4;t++){
        int row = wc*64 + t*16 + (lane & 15);
        int inner = (ks*32 + (lane>>4)*8)*2;
        bfr[t] = *(const bf16x8*)(LB + row*128 + (inner ^ ((row&7)<<4)));
      }
      #pragma unroll
      for (int s=0;s<4;s++)
        #pragma unroll
        for (int t=0;t<4;t++)
          acc[s][t] = mfma16(af[s], bfr[t], acc[s][t]);
    }
    drain_vm();          // publish next tile's global_load_lds before the barrier
    __syncthreads();
  }

  if (g.mode == 2){
    float* C = (float*)g.C;
    #pragma unroll
    for (int t=0;t<4;t++){
      int col = n0 + wc*64 + t*16 + (lane&15);
      float bv = g.bias[col];
      #pragma unroll
      for (int s=0;s<4;s++){
        #pragma unroll
        for (int r=0;r<4;r++){
          int row = m0 + wr*64 + s*16 + (lane>>4)*4 + r;
          C[(size_t)row*512 + col] = acc[s][t][r] + bv;
        }
      }
    }
  } else if (g.mode == 0){
    unsigned short* C = (unsigned short*)g.C;
    #pragma unroll
    for (int t=0;t<4;t++){
      int col = n0 + wc*64 + t*16 + (lane&15);
      float bv = g.bias[col];
      #pragma unroll
      for (int s=0;s<4;s++){
        #pragma unroll
        for (int r=0;r<4;r++){
          int row = m0 + wr*64 + s*16 + (lane>>4)*4 + r;
          C[(size_t)row*512 + col] = f2bf((acc[s][t][r] + bv) * g.scale);
        }
      }
    }
  } else {
    // transposed epilogue: C tile -> LDS [col][136] -> Vt[b*8+h][d][2048]
    __syncthreads();
    unsigned short* T = (unsigned short*)lds;
    #pragma unroll
    for (int s=0;s<4;s++){
      #pragma unroll
      for (int t=0;t<4;t++){
        int col  = wc*64 + t*16 + (lane&15);
        int rowb = wr*64 + s*16 + (lane>>4)*4;
        float bv = g.bias[n0+col];
        ushort4 pk;
        pk.x = f2bf(acc[s][t][0] + bv);
        pk.y = f2bf(acc[s][t][1] + bv);
        pk.z = f2bf(acc[s][t][2] + bv);
        pk.w = f2bf(acc[s][t][3] + bv);
        *(ushort4*)(T + col*136 + rowb) = pk;
      }
    }
    __syncthreads();
    unsigned short* Vt = (unsigned short*)g.C;
    int col = tid >> 1, half = tid & 1;
    int gcol = n0 + col;
    int hh = gcol >> 6, d = gcol & 63;
    int b = m0 >> 11, ms = m0 & 2047;
    unsigned short* dst = Vt + (((size_t)(b*8+hh)*64 + d)*2048 + ms + half*64);
    const unsigned short* srcT = T + col*136 + half*64;
    #pragma unroll
    for (int j=0;j<8;j++)
      *(int4*)(dst + j*8) = *(const int4*)(srcT + j*8);
  }
}

// ---------------- flash attention: barrier-free, all operands direct-to-register ----
// kv-row permutation rho(cb,lq) = (lq>>2)*8 + cb*4 + (lq&3) is folded into the K
// load address. Consequence: lane (g,lq)'s QK^T outputs p[cb][r] are PV A-slots
// j=cb*4+r for k-rows g*8+j, so the V B-fragment is ONE contiguous 16B read
// Vt[d][t*32+g*8]. No LDS staging, no __syncthreads, waves fully independent;
// register double-buffer (A/B sets) gives 1-tile prefetch depth with a natural
// counted vmcnt via register dependencies.
// Qs: [B][N][E] bf16 (pre-scaled by 1/8), Kb: [B][N][E] bf16, Vt: [B*H][64][2048]
__global__ __launch_bounds__(256) void attn_kernel(
    const unsigned short* __restrict__ Qs,
    const unsigned short* __restrict__ Kb,
    const unsigned short* __restrict__ Vt,
    unsigned short* __restrict__ AO)
{
  __shared__ float scratch[4][16];   // per-wave corr / 1/l broadcast (wave-private)
  const int tid = threadIdx.x, lane = tid & 63, wid = tid >> 6;
  const int bh = blockIdx.y;
  const int b = bh >> 3, h = bh & 7;
  const int q0 = blockIdx.x*64 + wid*16;   // 16 q-rows per wave
  const int lq = lane & 15;                // q-column owned by this lane
  const int g  = lane >> 4;                // lane group

  const unsigned short* Kbase = Kb + (size_t)b*2048*512 + h*64;
  const unsigned short* Vbase = Vt + (size_t)bh*64*2048;

  // Q fragments (B-operand of swapped QK^T)
  bf16x8 qf[2];
  #pragma unroll
  for (int c=0;c<2;c++)
    qf[c] = *(const bf16x8*)(Qs + (size_t)(b*2048 + q0 + lq)*512 + h*64 + c*32 + g*8);

  f32x4 o[4];
  #pragma unroll
  for (int dt=0;dt<4;dt++) o[dt] = (f32x4){0.f,0.f,0.f,0.f};
  float m_run = -1e30f, l_run = 0.f;

  const int krow0 = (lq>>2)*8 + (lq&3);        // rho(cb=0, lq)
  const int krow1 = krow0 + 4;                 // rho(cb=1, lq)

  auto loadK = [&](int t, bf16x8 (&kb)[2][2]){
    #pragma unroll
    for (int c=0;c<2;c++){
      kb[0][c] = *(const bf16x8*)(Kbase + (size_t)(t*32 + krow0)*512 + c*32 + g*8);
      kb[1][c] = *(const bf16x8*)(Kbase + (size_t)(t*32 + krow1)*512 + c*32 + g*8);
    }
  };
  auto loadV = [&](int t, bf16x8 (&vfr)[4]){
    #pragma unroll
    for (int dt=0;dt<4;dt++)
      vfr[dt] = *(const bf16x8*)(Vbase + (size_t)(dt*16+lq)*2048 + t*32 + g*8);
  };

  const float LOG2E = 1.44269504f;

  auto compute = [&](bf16x8 (&kb)[2][2], bf16x8 (&vfr)[4]){
    f32x4 S[2];
    #pragma unroll
    for (int cb=0;cb<2;cb++){
      f32x4 z = (f32x4){0.f,0.f,0.f,0.f};
      z = mfma16(kb[cb][0], qf[0], z);
      z = mfma16(kb[cb][1], qf[1], z);
      S[cb] = z;
    }

    // tile max: 7 in-reg fmax + 2 cross-group shuffles
    float mt = fmaxf(fmaxf(fmaxf(S[0][0],S[0][1]),fmaxf(S[0][2],S[0][3])),
                     fmaxf(fmaxf(S[1][0],S[1][1]),fmaxf(S[1][2],S[1][3])));
    mt = fmaxf(mt, __shfl_xor(mt, 16));
    mt = fmaxf(mt, __shfl_xor(mt, 32));

    // defer-max: rescale only when the running max grew by > 8
    if (!__all(mt <= m_run + 8.0f)){
      float mn = fmaxf(m_run, mt);
      float corr = exp2f((m_run-mn)*LOG2E);
      l_run *= corr;
      m_run = mn;
      if (lane < 16) scratch[wid][lq] = corr;   // q-domain -> o-domain transpose
      f32x4 c4 = *(const f32x4*)(&scratch[wid][g*4]);
      #pragma unroll
      for (int dt=0;dt<4;dt++)
        #pragma unroll
        for (int r=0;r<4;r++) o[dt][r] *= c4[r];
    }

    float mc = m_run*LOG2E;
    float p[2][4];
    #pragma unroll
    for (int cb=0;cb<2;cb++)
      #pragma unroll
      for (int r=0;r<4;r++)
        p[cb][r] = exp2f(S[cb][r]*LOG2E - mc);

    float rs = ((p[0][0]+p[0][1])+(p[0][2]+p[0][3]))
             + ((p[1][0]+p[1][1])+(p[1][2]+p[1][3]));
    rs += __shfl_xor(rs, 16);
    rs += __shfl_xor(rs, 32);
    l_run += rs;

    // P fragment directly in registers (slot j = cb*4+r)
    bf16x8 pf;
    #pragma unroll
    for (int cb=0;cb<2;cb++)
      #pragma unroll
      for (int r=0;r<4;r++)
        pf[cb*4+r] = (__bf16)p[cb][r];

    #pragma unroll
    for (int dt=0;dt<4;dt++)
      o[dt] = mfma16(pf, vfr[dt], o[dt]);
  };

  bf16x8 kA[2][2], vA[4], kB[2][2], vB[4];
  loadK(0, kA); loadV(0, vA);

  for (int t=0; t<64; t+=2){
    loadK(t+1, kB); loadV(t+1, vB);      // prefetch odd tile
    compute(kA, vA);
    if (t < 62){ loadK(t+2, kA); loadV(t+2, vA); }   // prefetch next even tile
    compute(kB, vB);
  }

  // epilogue: normalize and write AO [b][n][h*64+d]
  {
    if (lane < 16) scratch[wid][lq] = 1.0f / l_run;
    f32x4 li = *(const f32x4*)(&scratch[wid][g*4]);
    #pragma unroll
    for (int dt=0;dt<4;dt++){
      int col = h*64 + dt*16 + lq;
      #pragma unroll
      for (int r=0;r<4;r++){
        int row = b*2048 + q0 + g*4 + r;
        AO[(size_t)row*512 + col] = f2bf(o[dt][r] * li[r]);
      }
    }
  }
}

extern "C" void kernel_launch(void* const* d_in, const int* in_sizes, int n_in,
                              void* d_out, int out_size, void* d_ws, size_t ws_size,
                              hipStream_t stream)
{
  const float* q  = (const float*)d_in[0];
  const float* k  = (const float*)d_in[1];
  const float* v  = (const float*)d_in[2];
  const float* Wq = (const float*)d_in[3];
  const float* bq = (const float*)d_in[4];
  const float* Wk = (const float*)d_in[5];
  const float* bk = (const float*)d_in[6];
  const float* Wv = (const float*)d_in[7];
  const float* bv = (const float*)d_in[8];
  const float* Wo = (const float*)d_in[9];
  const float* bo = (const float*)d_in[10];

  unsigned short* X   = (unsigned short*)d_ws;
  unsigned short* Xq  = X;
  unsigned short* Xk  = X + NX;
  unsigned short* Xv  = X + 2*(size_t)NX;
  unsigned short* WqB = X + 3*(size_t)NX;
  unsigned short* WkB = WqB + NW;
  unsigned short* WvB = WqB + 2*(size_t)NW;
  unsigned short* WoB = WqB + 3*(size_t)NW;
  unsigned short* QS  = WqB + 4*(size_t)NW;
  unsigned short* KB  = QS + NX;
  unsigned short* VT  = KB + NX;
  unsigned short* AO  = VT + NX;

  convert_all<<<dim3(2048), dim3(256), 0, stream>>>(q, k, v, Wq, Wk, Wv, Wo, X);

  GArg gq{Xq, WqB, bq, (void*)QS, 0.125f, 0};   // SCALE folded into Q
  GArg gk{Xk, WkB, bk, (void*)KB, 1.0f,   0};
  GArg gv{Xv, WvB, bv, (void*)VT, 1.0f,   1};   // transposed epilogue
  gemm_bt<<<dim3(4, 64, 3), dim3(256), 0, stream>>>(gq, gk, gv);

  attn_kernel<<<dim3(32, 32), dim3(256), 0, stream>>>(QS, KB, VT, AO);

  GArg go{AO, WoB, bo, d_out, 1.0f, 2};
  gemm_bt<<<dim3(4, 64, 1), dim3(256), 0, stream>>>(go, go, go);
}

// Round 7
// 121.002 us; speedup vs baseline: 2.3148x; 2.3148x over previous
//
#include <hip/hip_runtime.h>
#include <stdint.h>

#define NX (8192*512)   // elements of one (B*N, E) matrix
#define NW (512*512)    // elements of one weight matrix

typedef __bf16 bf16x8 __attribute__((ext_vector_type(8)));
typedef float  f32x4  __attribute__((ext_vector_type(4)));
typedef float  f32x16 __attribute__((ext_vector_type(16)));

__device__ __forceinline__ unsigned short f2bf(float f){
  unsigned u = __builtin_bit_cast(unsigned, f);
  u += 0x7FFFu + ((u >> 16) & 1u);   // RNE
  return (unsigned short)(u >> 16);
}

__device__ __forceinline__ f32x4 mfma16(bf16x8 a, bf16x8 b, f32x4 c){
  return __builtin_amdgcn_mfma_f32_16x16x32_bf16(a, b, c, 0, 0, 0);
}
__device__ __forceinline__ f32x16 mfma32(bf16x8 a, bf16x8 b, f32x16 c){
  return __builtin_amdgcn_mfma_f32_32x32x16_bf16(a, b, c, 0, 0, 0);
}

__device__ __forceinline__ void gload_lds16(const void* g, void* l){
  __builtin_amdgcn_global_load_lds((const __attribute__((address_space(1))) void*)g,
                                   (__attribute__((address_space(3))) void*)l, 16, 0, 0);
}

#define VMCNT(n) asm volatile("s_waitcnt vmcnt(" #n ")" ::: "memory")

// ---------------- fp32 -> bf16 conversion of X (q,k,v) and weights ----------------
__global__ void convert_all(const float* __restrict__ q, const float* __restrict__ k,
                            const float* __restrict__ v, const float* __restrict__ wq,
                            const float* __restrict__ wk, const float* __restrict__ wv,
                            const float* __restrict__ wo, unsigned short* __restrict__ dst)
{
  const long total4 = (3L*NX + 4L*NW) / 4;
  for (long i = (long)blockIdx.x*blockDim.x + threadIdx.x; i < total4; i += (long)gridDim.x*blockDim.x){
    long e = i*4;
    const float* src; long off;
    if (e < NX)            { src = q;  off = e; }
    else if (e < 2L*NX)    { src = k;  off = e - NX; }
    else if (e < 3L*NX)    { src = v;  off = e - 2L*NX; }
    else {
      long w = e - 3L*NX; int wi = (int)(w / NW); off = w - (long)wi*NW;
      src = (wi==0) ? wq : (wi==1) ? wk : (wi==2) ? wv : wo;
    }
    float4 f = *(const float4*)(src + off);
    ushort4 o; o.x=f2bf(f.x); o.y=f2bf(f.y); o.z=f2bf(f.z); o.w=f2bf(f.w);
    *(ushort4*)(dst + e) = o;
  }
}

// ---------------- bf16 GEMM: C[m][n] = sum_k A[m][k]*B[n][k] (+bias) ----------------
struct GArg {
  const unsigned short* A;
  const unsigned short* B;
  const float* bias;
  void* C;
  float scale;
  int mode;
};

__global__ __launch_bounds__(256) void gemm_bt(GArg g0, GArg g1, GArg g2)
{
  GArg g = (blockIdx.z==0) ? g0 : (blockIdx.z==1) ? g1 : g2;
  __shared__ __attribute__((aligned(16))) unsigned char lds[65536];
  const int tid  = threadIdx.x;
  const int lane = tid & 63;
  const int wid  = tid >> 6;
  const int wr = wid >> 1, wc = wid & 1;
  const int m0 = blockIdx.y * 128;
  const int n0 = blockIdx.x * 128;

  f32x4 acc[4][4];
  #pragma unroll
  for (int s=0;s<4;s++)
    #pragma unroll
    for (int t=0;t<4;t++) acc[s][t] = (f32x4){0.f,0.f,0.f,0.f};

  auto stage = [&](int kt, int buf){
    int Lb = tid*16;
    #pragma unroll
    for (int i=0;i<4;i++){
      int L = Lb + i*4096;
      int row = L >> 7;
      int innerS = (L & 127) ^ ((row & 7) << 4);   // pre-swizzled source (T2)
      gload_lds16(g.A + (size_t)(m0+row)*512 + kt*64 + (innerS>>1), lds + buf*16384 + L);
    }
    #pragma unroll
    for (int i=0;i<4;i++){
      int L = Lb + i*4096;
      int row = L >> 7;
      int innerS = (L & 127) ^ ((row & 7) << 4);
      gload_lds16(g.B + (size_t)(n0+row)*512 + kt*64 + (innerS>>1), lds + 32768 + buf*16384 + L);
    }
  };

  stage(0, 0);
  VMCNT(0);
  __syncthreads();

  for (int kt=0; kt<8; kt++){
    int cur = kt & 1;
    if (kt < 7) stage(kt+1, cur^1);
    const unsigned char* LA = lds + cur*16384;
    const unsigned char* LB = lds + 32768 + cur*16384;
    #pragma unroll
    for (int ks=0; ks<2; ks++){
      bf16x8 af[4], bfr[4];
      #pragma unroll
      for (int s=0;s<4;s++){
        int row = wr*64 + s*16 + (lane & 15);
        int inner = (ks*32 + (lane>>4)*8)*2;
        af[s] = *(const bf16x8*)(LA + row*128 + (inner ^ ((row&7)<<4)));
      }
      #pragma unroll
      for (int t=0;t<4;t++){
        int row = wc*64 + t*16 + (lane & 15);
        int inner = (ks*32 + (lane>>4)*8)*2;
        bfr[t] = *(const bf16x8*)(LB + row*128 + (inner ^ ((row&7)<<4)));
      }
      #pragma unroll
      for (int s=0;s<4;s++)
        #pragma unroll
        for (int t=0;t<4;t++)
          acc[s][t] = mfma16(af[s], bfr[t], acc[s][t]);
    }
    VMCNT(0);            // publish next tile's global_load_lds before the barrier
    __syncthreads();
  }

  if (g.mode == 2){
    float* C = (float*)g.C;
    #pragma unroll
    for (int t=0;t<4;t++){
      int col = n0 + wc*64 + t*16 + (lane&15);
      float bv = g.bias[col];
      #pragma unroll
      for (int s=0;s<4;s++){
        #pragma unroll
        for (int r=0;r<4;r++){
          int row = m0 + wr*64 + s*16 + (lane>>4)*4 + r;
          C[(size_t)row*512 + col] = acc[s][t][r] + bv;
        }
      }
    }
  } else if (g.mode == 0){
    unsigned short* C = (unsigned short*)g.C;
    #pragma unroll
    for (int t=0;t<4;t++){
      int col = n0 + wc*64 + t*16 + (lane&15);
      float bv = g.bias[col];
      #pragma unroll
      for (int s=0;s<4;s++){
        #pragma unroll
        for (int r=0;r<4;r++){
          int row = m0 + wr*64 + s*16 + (lane>>4)*4 + r;
          C[(size_t)row*512 + col] = f2bf((acc[s][t][r] + bv) * g.scale);
        }
      }
    }
  } else {
    // transposed epilogue: C tile -> LDS [col][136] -> Vt[b*8+h][d][2048]
    __syncthreads();
    unsigned short* T = (unsigned short*)lds;
    #pragma unroll
    for (int s=0;s<4;s++){
      #pragma unroll
      for (int t=0;t<4;t++){
        int col  = wc*64 + t*16 + (lane&15);
        int rowb = wr*64 + s*16 + (lane>>4)*4;
        float bv = g.bias[n0+col];
        ushort4 pk;
        pk.x = f2bf(acc[s][t][0] + bv);
        pk.y = f2bf(acc[s][t][1] + bv);
        pk.z = f2bf(acc[s][t][2] + bv);
        pk.w = f2bf(acc[s][t][3] + bv);
        *(ushort4*)(T + col*136 + rowb) = pk;
      }
    }
    __syncthreads();
    unsigned short* Vt = (unsigned short*)g.C;
    int col = tid >> 1, half = tid & 1;
    int gcol = n0 + col;
    int hh = gcol >> 6, d = gcol & 63;
    int b = m0 >> 11, ms = m0 & 2047;
    unsigned short* dst = Vt + (((size_t)(b*8+hh)*64 + d)*2048 + ms + half*64);
    const unsigned short* srcT = T + col*136 + half*64;
    #pragma unroll
    for (int j=0;j<8;j++)
      *(int4*)(dst + j*8) = *(const int4*)(srcT + j*8);
  }
}

// ---------------- flash attention: 32x32 MFMA, lane-scalar softmax, counted vmcnt ----
// Swapped S^T = mfma32(K, Q): C col = q (lane&31), rows = 16 kv in regs.
// kv-label perm A(L) = (L&3)+4*((L>>3)&1)+8*((L>>2)&1)+16*((L>>4)&1) folded into
// K staging row order so S regs r=cb*8+j ARE the PV B-operand slot j of call cb
// (actual kv = 16cb+8hi+j), and V reads stay contiguous/identity. P never leaves
// registers; m/l/corr are lane-scalar (one xor32 shuffle per reduction).
// Pipeline: K 3-deep via global_load_lds + counted VMCNT(2); V reg-staged (T14).
// Qs: [B][N][E] bf16 (pre-scaled by 1/8), Kb: [B][N][E], Vt: [B*H][64][2048]
__global__ __launch_bounds__(256) void attn_kernel(
    const unsigned short* __restrict__ Qs,
    const unsigned short* __restrict__ Kb,
    const unsigned short* __restrict__ Vt,
    unsigned short* __restrict__ AO)
{
  // LDS: 0..12287   K bufs [3][32 rows][128B] (XOR-swizzled via source)
  //      12288..22527 V bufs [2][64 d][80B]
  __shared__ __attribute__((aligned(16))) unsigned char lds[22528];
  const int tid = threadIdx.x, lane = tid & 63, wid = tid >> 6;
  const int hi = lane >> 5, lq = lane & 31;

  // XCD-grouped work swizzle: 512 blocks, each XCD (flat%8) owns 4 whole bh
  const int flat = blockIdx.y*16 + blockIdx.x;
  const int work = (flat & 7)*64 + (flat >> 3);
  const int bh = work >> 4, qtile = work & 15;
  const int b = bh >> 3, h = bh & 7;
  const int q0 = qtile*128 + wid*32;

  const unsigned short* Kbase = Kb + (size_t)b*2048*512 + h*64;
  const unsigned short* Vbase = Vt + (size_t)bh*64*2048;
  unsigned char* VLDS = lds + 12288;

  // Q fragments (B-operand): lane holds Q[q0+lq][d = c*16 + 8hi + j]
  bf16x8 qf[4];
  #pragma unroll
  for (int c=0;c<4;c++)
    qf[c] = *(const bf16x8*)(Qs + (size_t)(b*2048 + q0 + lq)*512 + h*64 + c*16 + hi*8);

  // per-lane LDS read offsets
  int koff[4], voff[2][2];
  #pragma unroll
  for (int c=0;c<4;c++)
    koff[c] = lq*128 + ((c*32 + hi*16) ^ ((lq & 7) << 4));
  #pragma unroll
  for (int dh=0;dh<2;dh++)
    #pragma unroll
    for (int cb=0;cb<2;cb++)
      voff[dh][cb] = (dh*32 + lq)*80 + cb*32 + hi*16;

  // staging geometry
  const int sL = tid >> 3;                  // K LDS row staged by this thread
  const int sI = (tid & 7) * 16;            // byte within row
  const int sArow = (sL&3) + 4*((sL>>3)&1) + 8*((sL>>2)&1) + 16*((sL>>4)&1);
  const int sSrc = ((sI ^ ((sL & 7) << 4)) >> 1);   // swizzled source short offset
  const int vrow = tid >> 2, vpart = tid & 3;

  auto stageK = [&](int t, int buf){
    gload_lds16(Kbase + (size_t)(t*32 + sArow)*512 + sSrc, lds + buf*4096 + tid*16);
  };
  auto loadV = [&](int t){
    return *(const uint4*)(Vbase + (size_t)vrow*2048 + t*32 + vpart*8);
  };
  auto writeV = [&](int buf, uint4 v){
    *(uint4*)(VLDS + buf*5120 + vrow*80 + vpart*16) = v;
  };

  f32x16 o[2];
  o[0] = (f32x16)(0.f); o[1] = (f32x16)(0.f);
  float m_run = -1e30f, l_run = 0.f;
  const float LOG2E = 1.44269504f;

  auto compute = [&](const unsigned char* KL, const unsigned char* VL){
    f32x16 S = (f32x16)(0.f);
    #pragma unroll
    for (int c=0;c<4;c++){
      bf16x8 kf = *(const bf16x8*)(KL + koff[c]);
      S = mfma32(kf, qf[c], S);
    }

    float mt = fmaxf(S[0], S[1]);
    #pragma unroll
    for (int r=2;r<16;r++) mt = fmaxf(mt, S[r]);
    mt = fmaxf(mt, __shfl_xor(mt, 32));

    if (!__all(mt <= m_run + 8.0f)){
      float mn = fmaxf(m_run, mt);
      float corr = exp2f((m_run - mn)*LOG2E);
      l_run *= corr;
      m_run = mn;
      #pragma unroll
      for (int r=0;r<16;r++){ o[0][r] *= corr; o[1][r] *= corr; }
    }

    float mc = m_run * LOG2E;
    float p[16];
    #pragma unroll
    for (int r=0;r<16;r++) p[r] = exp2f(S[r]*LOG2E - mc);

    float rs = p[0] + p[1];
    #pragma unroll
    for (int r=2;r<16;r++) rs += p[r];
    rs += __shfl_xor(rs, 32);
    l_run += rs;

    bf16x8 pf0, pf1;
    #pragma unroll
    for (int j=0;j<8;j++){ pf0[j] = (__bf16)p[j]; pf1[j] = (__bf16)p[8+j]; }

    #pragma unroll
    for (int dh=0;dh<2;dh++){
      bf16x8 v0 = *(const bf16x8*)(VL + voff[dh][0]);
      o[dh] = mfma32(v0, pf0, o[dh]);
      bf16x8 v1 = *(const bf16x8*)(VL + voff[dh][1]);
      o[dh] = mfma32(v1, pf1, o[dh]);
    }
  };

  // prologue
  stageK(0, 0); stageK(1, 1);
  uint4 VgA = loadV(0);
  uint4 VgB = loadV(1);
  VMCNT(1);                 // K0,K1,VgA landed; VgB may be in flight
  writeV(0, VgA);
  __syncthreads();

  for (int t=0; t<62; t+=2){
    // even iter t
    stageK(t+2, (t+2)%3); VgA = loadV(t+2);
    compute(lds + (t%3)*4096, VLDS);
    VMCNT(2);               // K(t+1),VgB(t+1) landed; K(t+2),VgA(t+2) in flight
    writeV(1, VgB);
    __syncthreads();
    // odd iter t+1
    stageK(t+3, (t+3)%3); VgB = loadV(t+3);
    compute(lds + ((t+1)%3)*4096, VLDS + 5120);
    VMCNT(2);
    writeV(0, VgA);
    __syncthreads();
  }
  // t = 62
  compute(lds + 2*4096, VLDS);
  VMCNT(0);
  writeV(1, VgB);
  __syncthreads();
  // t = 63
  compute(lds + 0*4096, VLDS + 5120);

  // epilogue: lane-scalar normalize; write AO[b][q0+lq][h*64 + d]
  {
    float inv = 1.0f / l_run;
    unsigned short* dst = AO + (size_t)(b*2048 + q0 + lq)*512 + h*64;
    #pragma unroll
    for (int dh=0;dh<2;dh++){
      #pragma unroll
      for (int g2=0;g2<4;g2++){
        ushort4 pk;
        pk.x = f2bf(o[dh][g2*4+0]*inv);
        pk.y = f2bf(o[dh][g2*4+1]*inv);
        pk.z = f2bf(o[dh][g2*4+2]*inv);
        pk.w = f2bf(o[dh][g2*4+3]*inv);
        *(ushort4*)(dst + dh*32 + g2*8 + hi*4) = pk;
      }
    }
  }
}

extern "C" void kernel_launch(void* const* d_in, const int* in_sizes, int n_in,
                              void* d_out, int out_size, void* d_ws, size_t ws_size,
                              hipStream_t stream)
{
  const float* q  = (const float*)d_in[0];
  const float* k  = (const float*)d_in[1];
  const float* v  = (const float*)d_in[2];
  const float* Wq = (const float*)d_in[3];
  const float* bq = (const float*)d_in[4];
  const float* Wk = (const float*)d_in[5];
  const float* bk = (const float*)d_in[6];
  const float* Wv = (const float*)d_in[7];
  const float* bv = (const float*)d_in[8];
  const float* Wo = (const float*)d_in[9];
  const float* bo = (const float*)d_in[10];

  unsigned short* X   = (unsigned short*)d_ws;
  unsigned short* Xq  = X;
  unsigned short* Xk  = X + NX;
  unsigned short* Xv  = X + 2*(size_t)NX;
  unsigned short* WqB = X + 3*(size_t)NX;
  unsigned short* WkB = WqB + NW;
  unsigned short* WvB = WqB + 2*(size_t)NW;
  unsigned short* WoB = WqB + 3*(size_t)NW;
  unsigned short* QS  = WqB + 4*(size_t)NW;
  unsigned short* KB  = QS + NX;
  unsigned short* VT  = KB + NX;
  unsigned short* AO  = VT + NX;

  convert_all<<<dim3(2048), dim3(256), 0, stream>>>(q, k, v, Wq, Wk, Wv, Wo, X);

  GArg gq{Xq, WqB, bq, (void*)QS, 0.125f, 0};   // SCALE folded into Q
  GArg gk{Xk, WkB, bk, (void*)KB, 1.0f,   0};
  GArg gv{Xv, WvB, bv, (void*)VT, 1.0f,   1};   // transposed epilogue
  gemm_bt<<<dim3(4, 64, 3), dim3(256), 0, stream>>>(gq, gk, gv);

  attn_kernel<<<dim3(16, 32), dim3(256), 0, stream>>>(QS, KB, VT, AO);

  GArg go{AO, WoB, bo, d_out, 1.0f, 2};
  gemm_bt<<<dim3(4, 64, 1), dim3(256), 0, stream>>>(go, go, go);
}

// Round 9
// 119.061 us; speedup vs baseline: 2.3526x; 1.0163x over previous
//
#include <hip/hip_runtime.h>
#include <stdint.h>

#define NX (8192*512)   // elements of one (B*N, E) matrix
#define NW (512*512)    // elements of one weight matrix

typedef __bf16 bf16x8 __attribute__((ext_vector_type(8)));
typedef float  f32x4  __attribute__((ext_vector_type(4)));
typedef float  f32x16 __attribute__((ext_vector_type(16)));

__device__ __forceinline__ unsigned short f2bf(float f){
  unsigned u = __builtin_bit_cast(unsigned, f);
  u += 0x7FFFu + ((u >> 16) & 1u);   // RNE
  return (unsigned short)(u >> 16);
}

__device__ __forceinline__ f32x4 mfma16(bf16x8 a, bf16x8 b, f32x4 c){
  return __builtin_amdgcn_mfma_f32_16x16x32_bf16(a, b, c, 0, 0, 0);
}
__device__ __forceinline__ f32x16 mfma32(bf16x8 a, bf16x8 b, f32x16 c){
  return __builtin_amdgcn_mfma_f32_32x32x16_bf16(a, b, c, 0, 0, 0);
}

__device__ __forceinline__ void gload_lds16(const void* g, void* l){
  __builtin_amdgcn_global_load_lds((const __attribute__((address_space(1))) void*)g,
                                   (__attribute__((address_space(3))) void*)l, 16, 0, 0);
}

#define VMCNT(n) asm volatile("s_waitcnt vmcnt(" #n ")" ::: "memory")

// ---------------- fp32 -> bf16 conversion of X (q,k,v) and weights ----------------
__global__ void convert_all(const float* __restrict__ q, const float* __restrict__ k,
                            const float* __restrict__ v, const float* __restrict__ wq,
                            const float* __restrict__ wk, const float* __restrict__ wv,
                            const float* __restrict__ wo, unsigned short* __restrict__ dst)
{
  const long total4 = (3L*NX + 4L*NW) / 4;
  for (long i = (long)blockIdx.x*blockDim.x + threadIdx.x; i < total4; i += (long)gridDim.x*blockDim.x){
    long e = i*4;
    const float* src; long off;
    if (e < NX)            { src = q;  off = e; }
    else if (e < 2L*NX)    { src = k;  off = e - NX; }
    else if (e < 3L*NX)    { src = v;  off = e - 2L*NX; }
    else {
      long w = e - 3L*NX; int wi = (int)(w / NW); off = w - (long)wi*NW;
      src = (wi==0) ? wq : (wi==1) ? wk : (wi==2) ? wv : wo;
    }
    float4 f = *(const float4*)(src + off);
    ushort4 o; o.x=f2bf(f.x); o.y=f2bf(f.y); o.z=f2bf(f.z); o.w=f2bf(f.w);
    *(ushort4*)(dst + e) = o;
  }
}

// ---------------- bf16 GEMM: C[m][n] = sum_k A[m][k]*B[n][k] (+bias) ----------------
struct GArg {
  const unsigned short* A;
  const unsigned short* B;
  const float* bias;
  void* C;
  float scale;
  int mode;
};

__global__ __launch_bounds__(256) void gemm_bt(GArg g0, GArg g1, GArg g2)
{
  GArg g = (blockIdx.z==0) ? g0 : (blockIdx.z==1) ? g1 : g2;
  __shared__ __attribute__((aligned(16))) unsigned char lds[65536];
  const int tid  = threadIdx.x;
  const int lane = tid & 63;
  const int wid  = tid >> 6;
  const int wr = wid >> 1, wc = wid & 1;
  const int m0 = blockIdx.y * 128;
  const int n0 = blockIdx.x * 128;

  f32x4 acc[4][4];
  #pragma unroll
  for (int s=0;s<4;s++)
    #pragma unroll
    for (int t=0;t<4;t++) acc[s][t] = (f32x4){0.f,0.f,0.f,0.f};

  auto stage = [&](int kt, int buf){
    int Lb = tid*16;
    #pragma unroll
    for (int i=0;i<4;i++){
      int L = Lb + i*4096;
      int row = L >> 7;
      int innerS = (L & 127) ^ ((row & 7) << 4);   // pre-swizzled source (T2)
      gload_lds16(g.A + (size_t)(m0+row)*512 + kt*64 + (innerS>>1), lds + buf*16384 + L);
    }
    #pragma unroll
    for (int i=0;i<4;i++){
      int L = Lb + i*4096;
      int row = L >> 7;
      int innerS = (L & 127) ^ ((row & 7) << 4);
      gload_lds16(g.B + (size_t)(n0+row)*512 + kt*64 + (innerS>>1), lds + 32768 + buf*16384 + L);
    }
  };

  stage(0, 0);
  VMCNT(0);
  __syncthreads();

  for (int kt=0; kt<8; kt++){
    int cur = kt & 1;
    if (kt < 7) stage(kt+1, cur^1);
    const unsigned char* LA = lds + cur*16384;
    const unsigned char* LB = lds + 32768 + cur*16384;
    #pragma unroll
    for (int ks=0; ks<2; ks++){
      bf16x8 af[4], bfr[4];
      #pragma unroll
      for (int s=0;s<4;s++){
        int row = wr*64 + s*16 + (lane & 15);
        int inner = (ks*32 + (lane>>4)*8)*2;
        af[s] = *(const bf16x8*)(LA + row*128 + (inner ^ ((row&7)<<4)));
      }
      #pragma unroll
      for (int t=0;t<4;t++){
        int row = wc*64 + t*16 + (lane & 15);
        int inner = (ks*32 + (lane>>4)*8)*2;
        bfr[t] = *(const bf16x8*)(LB + row*128 + (inner ^ ((row&7)<<4)));
      }
      #pragma unroll
      for (int s=0;s<4;s++)
        #pragma unroll
        for (int t=0;t<4;t++)
          acc[s][t] = mfma16(af[s], bfr[t], acc[s][t]);
    }
    VMCNT(0);            // publish next tile's global_load_lds before the barrier
    __syncthreads();
  }

  if (g.mode == 2){
    float* C = (float*)g.C;
    #pragma unroll
    for (int t=0;t<4;t++){
      int col = n0 + wc*64 + t*16 + (lane&15);
      float bv = g.bias[col];
      #pragma unroll
      for (int s=0;s<4;s++){
        #pragma unroll
        for (int r=0;r<4;r++){
          int row = m0 + wr*64 + s*16 + (lane>>4)*4 + r;
          C[(size_t)row*512 + col] = acc[s][t][r] + bv;
        }
      }
    }
  } else if (g.mode == 0){
    unsigned short* C = (unsigned short*)g.C;
    #pragma unroll
    for (int t=0;t<4;t++){
      int col = n0 + wc*64 + t*16 + (lane&15);
      float bv = g.bias[col];
      #pragma unroll
      for (int s=0;s<4;s++){
        #pragma unroll
        for (int r=0;r<4;r++){
          int row = m0 + wr*64 + s*16 + (lane>>4)*4 + r;
          C[(size_t)row*512 + col] = f2bf((acc[s][t][r] + bv) * g.scale);
        }
      }
    }
  } else {
    // transposed epilogue: C tile -> LDS [col][136] -> Vt[b*8+h][d][2048]
    __syncthreads();
    unsigned short* T = (unsigned short*)lds;
    #pragma unroll
    for (int s=0;s<4;s++){
      #pragma unroll
      for (int t=0;t<4;t++){
        int col  = wc*64 + t*16 + (lane&15);
        int rowb = wr*64 + s*16 + (lane>>4)*4;
        float bv = g.bias[n0+col];
        ushort4 pk;
        pk.x = f2bf(acc[s][t][0] + bv);
        pk.y = f2bf(acc[s][t][1] + bv);
        pk.z = f2bf(acc[s][t][2] + bv);
        pk.w = f2bf(acc[s][t][3] + bv);
        *(ushort4*)(T + col*136 + rowb) = pk;
      }
    }
    __syncthreads();
    unsigned short* Vt = (unsigned short*)g.C;
    int col = tid >> 1, half = tid & 1;
    int gcol = n0 + col;
    int hh = gcol >> 6, d = gcol & 63;
    int b = m0 >> 11, ms = m0 & 2047;
    unsigned short* dst = Vt + (((size_t)(b*8+hh)*64 + d)*2048 + ms + half*64);
    const unsigned short* srcT = T + col*136 + half*64;
    #pragma unroll
    for (int j=0;j<8;j++)
      *(int4*)(dst + j*8) = *(const int4*)(srcT + j*8);
  }
}

// ---------------- flash attention: 32x32 MFMA, log2-domain softmax, x-tile pipeline ----
// BISECT vs round 8 (NaN): cvt_pk asm -> scalar (__bf16) casts; __builtin_amdgcn_exp2f
// -> exp2f. Pipeline / log2 domain / max3 / vrow remap / 3-buf rotation KEPT.
__global__ __launch_bounds__(256) void attn_kernel(
    const unsigned short* __restrict__ Qs,
    const unsigned short* __restrict__ Kb,
    const unsigned short* __restrict__ Vt,
    unsigned short* __restrict__ AO)
{
  // LDS: 0..12287 K bufs [3][32 rows][128B]; 12288..27647 V bufs [3][64 d][80B]
  __shared__ __attribute__((aligned(16))) unsigned char lds[27648];
  const int tid = threadIdx.x, lane = tid & 63, wid = tid >> 6;
  const int hi = lane >> 5, lq = lane & 31;

  // XCD-grouped work swizzle: each XCD (flat%8) owns 4 whole bh
  const int flat = blockIdx.y*16 + blockIdx.x;
  const int work = (flat & 7)*64 + (flat >> 3);
  const int bh = work >> 4, qtile = work & 15;
  const int b = bh >> 3, h = bh & 7;
  const int q0 = qtile*128 + wid*32;

  const unsigned short* Kbase = Kb + (size_t)b*2048*512 + h*64;
  const unsigned short* Vbase = Vt + (size_t)bh*64*2048;
  unsigned char* VLDS = lds + 12288;

  bf16x8 qf[4];
  #pragma unroll
  for (int c=0;c<4;c++)
    qf[c] = *(const bf16x8*)(Qs + (size_t)(b*2048 + q0 + lq)*512 + h*64 + c*16 + hi*8);

  int koff[4], voff[2][2];
  #pragma unroll
  for (int c=0;c<4;c++)
    koff[c] = lq*128 + ((c*32 + hi*16) ^ ((lq & 7) << 4));
  #pragma unroll
  for (int dh=0;dh<2;dh++)
    #pragma unroll
    for (int cb=0;cb<2;cb++)
      voff[dh][cb] = (dh*32 + lq)*80 + cb*32 + hi*16;

  // K staging geometry (kv-label perm in row order, XOR swizzle via source)
  const int sL = tid >> 3;
  const int sI = (tid & 7) * 16;
  const int sArow = (sL&3) + 4*((sL>>3)&1) + 8*((sL>>2)&1) + 16*((sL>>4)&1);
  const int sSrc = ((sI ^ ((sL & 7) << 4)) >> 1);
  // V staging: row = wid*16+(lane&15), part = lane>>4  (2-way bank phase, free)
  const int vrow = wid*16 + (lane & 15);
  const int vpart = lane >> 4;

  auto stageK = [&](int t, int buf){
    gload_lds16(Kbase + (size_t)(t*32 + sArow)*512 + sSrc, lds + buf*4096 + tid*16);
  };
  auto loadV = [&](int t){
    return *(const uint4*)(Vbase + (size_t)vrow*2048 + t*32 + vpart*8);
  };
  auto writeV = [&](int buf, uint4 v){
    *(uint4*)(VLDS + buf*5120 + vrow*80 + vpart*16) = v;
  };

  f32x16 o[2];
  o[0] = (f32x16)(0.f); o[1] = (f32x16)(0.f);
  float m_run = -1e30f, l_run = 0.f;

  auto qkt = [&](const unsigned char* KL) -> f32x16 {
    f32x16 S = (f32x16)(0.f);
    #pragma unroll
    for (int c=0;c<4;c++){
      bf16x8 kf = *(const bf16x8*)(KL + koff[c]);
      S = mfma32(kf, qf[c], S);
    }
    return S;
  };

  auto finish = [&](f32x16 S, const unsigned char* VL){
    // max via max3 tree (log2 domain)
    float a0 = fmaxf(fmaxf(S[0],S[1]),S[2]);
    float a1 = fmaxf(fmaxf(S[3],S[4]),S[5]);
    float a2 = fmaxf(fmaxf(S[6],S[7]),S[8]);
    float a3 = fmaxf(fmaxf(S[9],S[10]),S[11]);
    float a4 = fmaxf(fmaxf(S[12],S[13]),S[14]);
    float mt = fmaxf(fmaxf(fmaxf(a0,a1),a2), fmaxf(fmaxf(a3,a4),S[15]));
    mt = fmaxf(mt, __shfl_xor(mt, 32));

    if (!__all(mt <= m_run + 11.5415603f)){   // 8 nats in log2 units
      float mn = fmaxf(m_run, mt);
      float corr = exp2f(m_run - mn);
      l_run *= corr;
      m_run = mn;
      #pragma unroll
      for (int r=0;r<16;r++){ o[0][r] *= corr; o[1][r] *= corr; }
    }

    float p[16];
    #pragma unroll
    for (int r=0;r<16;r++) p[r] = exp2f(S[r] - m_run);

    float rs = (((p[0]+p[1])+(p[2]+p[3]))+((p[4]+p[5])+(p[6]+p[7])))
             + (((p[8]+p[9])+(p[10]+p[11]))+((p[12]+p[13])+(p[14]+p[15])));
    rs += __shfl_xor(rs, 32);
    l_run += rs;

    bf16x8 pf0, pf1;
    #pragma unroll
    for (int j=0;j<8;j++){ pf0[j] = (__bf16)p[j]; pf1[j] = (__bf16)p[8+j]; }

    #pragma unroll
    for (int dh=0;dh<2;dh++){
      bf16x8 v0 = *(const bf16x8*)(VL + voff[dh][0]);
      o[dh] = mfma32(v0, pf0, o[dh]);
      bf16x8 v1 = *(const bf16x8*)(VL + voff[dh][1]);
      o[dh] = mfma32(v1, pf1, o[dh]);
    }
  };

  // prologue: K0,K1 staged; V0,V1 staged; S(0) computed; K2 in flight
  stageK(0, 0); stageK(1, 1);
  uint4 VgA = loadV(0);
  VMCNT(0); writeV(0, VgA);
  __syncthreads();
  VgA = loadV(1); stageK(2, 2);
  f32x16 S_a = qkt(lds);              // S(0) from K buf 0
  VMCNT(1); writeV(1, VgA);           // V1 landed; K2 in flight
  __syncthreads();

  for (int t=0; t<62; t+=2){
    // half A: compute S(t+1), finish tile t
    VgA = loadV(t+2);
    stageK(t+3, t%3);                                  // (t+3)%3 == t%3
    f32x16 S_b = qkt(lds + ((t+1)%3)*4096);
    finish(S_a, VLDS + (t%3)*5120);
    VMCNT(1); writeV((t+2)%3, VgA);
    __syncthreads();
    // half B: compute S(t+2), finish tile t+1
    VgA = loadV(t+3);
    if (t < 60) stageK(t+4, (t+1)%3);
    S_a = qkt(lds + ((t+2)%3)*4096);
    finish(S_b, VLDS + ((t+1)%3)*5120);
    VMCNT(1); writeV((t+3)%3, VgA);
    __syncthreads();
  }
  // tail: S_a = S(62); K63,V62,V63 resident
  {
    f32x16 S_b = qkt(lds + 0*4096);    // K63 in buf 63%3 == 0
    finish(S_a, VLDS + 2*5120);        // V62 in buf 2
    finish(S_b, VLDS + 0*5120);        // V63 in buf 0
  }

  // epilogue: lane-scalar normalize; write AO[b][q0+lq][h*64 + d]
  {
    float inv = 1.0f / l_run;
    unsigned short* dst = AO + (size_t)(b*2048 + q0 + lq)*512 + h*64;
    #pragma unroll
    for (int dh=0;dh<2;dh++){
      #pragma unroll
      for (int g2=0;g2<4;g2++){
        ushort4 pk;
        pk.x = f2bf(o[dh][g2*4+0]*inv);
        pk.y = f2bf(o[dh][g2*4+1]*inv);
        pk.z = f2bf(o[dh][g2*4+2]*inv);
        pk.w = f2bf(o[dh][g2*4+3]*inv);
        *(ushort4*)(dst + dh*32 + g2*8 + hi*4) = pk;
      }
    }
  }
}

extern "C" void kernel_launch(void* const* d_in, const int* in_sizes, int n_in,
                              void* d_out, int out_size, void* d_ws, size_t ws_size,
                              hipStream_t stream)
{
  const float* q  = (const float*)d_in[0];
  const float* k  = (const float*)d_in[1];
  const float* v  = (const float*)d_in[2];
  const float* Wq = (const float*)d_in[3];
  const float* bq = (const float*)d_in[4];
  const float* Wk = (const float*)d_in[5];
  const float* bk = (const float*)d_in[6];
  const float* Wv = (const float*)d_in[7];
  const float* bv = (const float*)d_in[8];
  const float* Wo = (const float*)d_in[9];
  const float* bo = (const float*)d_in[10];

  unsigned short* X   = (unsigned short*)d_ws;
  unsigned short* Xq  = X;
  unsigned short* Xk  = X + NX;
  unsigned short* Xv  = X + 2*(size_t)NX;
  unsigned short* WqB = X + 3*(size_t)NX;
  unsigned short* WkB = WqB + NW;
  unsigned short* WvB = WqB + 2*(size_t)NW;
  unsigned short* WoB = WqB + 3*(size_t)NW;
  unsigned short* QS  = WqB + 4*(size_t)NW;
  unsigned short* KB  = QS + NX;
  unsigned short* VT  = KB + NX;
  unsigned short* AO  = VT + NX;

  convert_all<<<dim3(2048), dim3(256), 0, stream>>>(q, k, v, Wq, Wk, Wv, Wo, X);

  // Q scale = SCALE * log2(e): softmax runs in log2 domain
  GArg gq{Xq, WqB, bq, (void*)QS, 0.180336878f, 0};
  GArg gk{Xk, WkB, bk, (void*)KB, 1.0f,   0};
  GArg gv{Xv, WvB, bv, (void*)VT, 1.0f,   1};   // transposed epilogue
  gemm_bt<<<dim3(4, 64, 3), dim3(256), 0, stream>>>(gq, gk, gv);

  attn_kernel<<<dim3(16, 32), dim3(256), 0, stream>>>(QS, KB, VT, AO);

  GArg go{AO, WoB, bo, d_out, 1.0f, 2};
  gemm_bt<<<dim3(4, 64, 1), dim3(256), 0, stream>>>(go, go, go);
}